// Round 5
// baseline (215.445 us; speedup 1.0000x reference)
//
#include <hip/hip_runtime.h>

#define FDIM 16
#define SEG 128   // edges per 16-lane group

typedef int   vint4  __attribute__((ext_vector_type(4)));
typedef float vflt4  __attribute__((ext_vector_type(4)));

// ---------------------------------------------------------------------------
// Kernel 0: zero-fill d_out (hi accumulator). Own kernel (graph-capture-safe).
// ---------------------------------------------------------------------------
__global__ void zero_kernel(float4* __restrict__ p, long long n4) {
  long long i = (long long)blockIdx.x * blockDim.x + threadIdx.x;
  if (i < n4) p[i] = make_float4(0.f, 0.f, 0.f, 0.f);
}

// ---------------------------------------------------------------------------
// Kernel 1: sorted-COO SpMM  hi[r,:] += val[e] * x[col[e],:]
// 16 lanes/group = one lane per feature; group walks SEG contiguous edges in
// chunks of 8. Explicit 3-stage software pipeline:
//     iter i:  issue edge loads for chunk i+2 (nontemporal, streamed once)
//              issue x-gathers for chunk i+1 (cols already in regs)
//              process chunk i (FMAs + run-flush atomics)
// Distinct register buffers let the compiler emit counted vmcnt waits that
// only drain 2-iteration-old loads -> ~14 lines in flight per lane-group.
// Sorted rows: if last row of chunk == current run row, whole chunk is one
// run (branch-free fast path).
// ---------------------------------------------------------------------------
struct EdgeChunk {
  vint4 ra, rb;     // rows e..e+7
  vint4 ca, cb;     // cols e..e+7
  vflt4 va, vb;     // vals e..e+7
};
struct Gath {
  float g0, g1, g2, g3, g4, g5, g6, g7;
};

__device__ __forceinline__ EdgeChunk load_edges(const int* __restrict__ rows,
                                                const int* __restrict__ cols,
                                                const float* __restrict__ vals,
                                                long long e) {
  EdgeChunk c;
  c.ra = __builtin_nontemporal_load(reinterpret_cast<const vint4*>(rows + e));
  c.rb = __builtin_nontemporal_load(reinterpret_cast<const vint4*>(rows + e + 4));
  c.ca = __builtin_nontemporal_load(reinterpret_cast<const vint4*>(cols + e));
  c.cb = __builtin_nontemporal_load(reinterpret_cast<const vint4*>(cols + e + 4));
  c.va = __builtin_nontemporal_load(reinterpret_cast<const vflt4*>(vals + e));
  c.vb = __builtin_nontemporal_load(reinterpret_cast<const vflt4*>(vals + e + 4));
  return c;
}

__device__ __forceinline__ Gath gather_x(const float* __restrict__ x,
                                         const EdgeChunk& c, int f) {
  Gath g;
  g.g0 = x[c.ca.x * FDIM + f];
  g.g1 = x[c.ca.y * FDIM + f];
  g.g2 = x[c.ca.z * FDIM + f];
  g.g3 = x[c.ca.w * FDIM + f];
  g.g4 = x[c.cb.x * FDIM + f];
  g.g5 = x[c.cb.y * FDIM + f];
  g.g6 = x[c.cb.z * FDIM + f];
  g.g7 = x[c.cb.w * FDIM + f];
  return g;
}

__device__ __forceinline__ void process_chunk(const EdgeChunk& c, const Gath& g,
                                              int f, int& cur, float& acc,
                                              float* __restrict__ hi) {
#define FLUSH_STEP(r_, v_, x_)              \
  if (r_ != cur) {                          \
    atomicAdd(&hi[cur * FDIM + f], acc);    \
    acc = 0.f;                              \
    cur = r_;                               \
  }                                         \
  acc = fmaf(v_, x_, acc);

  if (c.rb.w == cur) {  // whole chunk continues current run (rows sorted)
    acc = fmaf(c.va.x, g.g0, acc);
    acc = fmaf(c.va.y, g.g1, acc);
    acc = fmaf(c.va.z, g.g2, acc);
    acc = fmaf(c.va.w, g.g3, acc);
    acc = fmaf(c.vb.x, g.g4, acc);
    acc = fmaf(c.vb.y, g.g5, acc);
    acc = fmaf(c.vb.z, g.g6, acc);
    acc = fmaf(c.vb.w, g.g7, acc);
  } else {
    FLUSH_STEP(c.ra.x, c.va.x, g.g0)
    FLUSH_STEP(c.ra.y, c.va.y, g.g1)
    FLUSH_STEP(c.ra.z, c.va.z, g.g2)
    FLUSH_STEP(c.ra.w, c.va.w, g.g3)
    FLUSH_STEP(c.rb.x, c.vb.x, g.g4)
    FLUSH_STEP(c.rb.y, c.vb.y, g.g5)
    FLUSH_STEP(c.rb.z, c.vb.z, g.g6)
    FLUSH_STEP(c.rb.w, c.vb.w, g.g7)
  }
#undef FLUSH_STEP
}

__global__ __launch_bounds__(256) void spmm_kernel(
    const int* __restrict__ rows,
    const int* __restrict__ cols,
    const float* __restrict__ vals,
    const float* __restrict__ x,
    float* __restrict__ hi,
    long long nedge) {
  long long gid = (long long)blockIdx.x * 16 + (threadIdx.x >> 4);
  int f = threadIdx.x & 15;
  long long e0 = gid * SEG;
  if (e0 >= nedge) return;
  long long e1 = e0 + SEG;
  if (e1 > nedge) e1 = nedge;
  long long len = e1 - e0;
  long long nfull = len >> 3;

  int cur = rows[e0];
  float acc = 0.f;
  long long e = e0;

  if (nfull >= 2) {
    EdgeChunk cA = load_edges(rows, cols, vals, e0);
    EdgeChunk cB = load_edges(rows, cols, vals, e0 + 8);
    Gath gA = gather_x(x, cA, f);
    long long it = 0;
    for (; it + 2 < nfull; ++it) {
      EdgeChunk cC = load_edges(rows, cols, vals, e0 + (it + 2) * 8);
      Gath gB = gather_x(x, cB, f);
      process_chunk(cA, gA, f, cur, acc, hi);
      cA = cB;
      cB = cC;
      gA = gB;
    }
    // two chunks remain: cA (gathers ready in gA) and cB
    Gath gB = gather_x(x, cB, f);
    process_chunk(cA, gA, f, cur, acc, hi);
    process_chunk(cB, gB, f, cur, acc, hi);
    e = e0 + nfull * 8;
  } else if (nfull == 1) {
    EdgeChunk cA = load_edges(rows, cols, vals, e0);
    Gath gA = gather_x(x, cA, f);
    process_chunk(cA, gA, f, cur, acc, hi);
    e = e0 + 8;
  }

  for (; e < e1; ++e) {  // scalar tail (empty when SEG | nedge)
    int r = rows[e];
    int c = cols[e];
    float v = vals[e];
    float xv = x[c * FDIM + f];
    if (r != cur) {
      atomicAdd(&hi[cur * FDIM + f], acc);
      acc = 0.f;
      cur = r;
    }
    acc = fmaf(v, xv, acc);
  }
  atomicAdd(&hi[cur * FDIM + f], acc);
}

// ---------------------------------------------------------------------------
// Kernel 2: per-node epilogue, in place on hio (= hi on input, out on output).
//   alpha = hi . fc_w + fc_b ; theta = log(lamda/l + 1)
//   s = concat(hi,h0) @ W ; out = theta*s + (1-theta)*((1-alpha)*hi+alpha*h0) + x
// ---------------------------------------------------------------------------
__global__ void fuse_kernel(float* __restrict__ hio,
                            const float* __restrict__ h0,
                            const float* __restrict__ x,
                            const float* __restrict__ weight,
                            const float* __restrict__ fc_w,
                            const float* __restrict__ fc_b,
                            const float* __restrict__ lamda,
                            const int* __restrict__ lpar,
                            int n) {
  int i = blockIdx.x * blockDim.x + threadIdx.x;
  if (i >= n) return;

  float theta = logf(lamda[0] / (float)lpar[0] + 1.0f);
  float fcb = fc_b[0];

  float hiv[FDIM], h0v[FDIM], xv[FDIM];
  {
    const float4* p = reinterpret_cast<const float4*>(hio + (size_t)i * FDIM);
    const float4* q = reinterpret_cast<const float4*>(h0 + (size_t)i * FDIM);
    const float4* r = reinterpret_cast<const float4*>(x + (size_t)i * FDIM);
#pragma unroll
    for (int j = 0; j < 4; ++j) {
      float4 a = p[j];
      hiv[4 * j + 0] = a.x; hiv[4 * j + 1] = a.y; hiv[4 * j + 2] = a.z; hiv[4 * j + 3] = a.w;
      float4 b = q[j];
      h0v[4 * j + 0] = b.x; h0v[4 * j + 1] = b.y; h0v[4 * j + 2] = b.z; h0v[4 * j + 3] = b.w;
      float4 c = r[j];
      xv[4 * j + 0] = c.x; xv[4 * j + 1] = c.y; xv[4 * j + 2] = c.z; xv[4 * j + 3] = c.w;
    }
  }

  float alpha = fcb;
#pragma unroll
  for (int k = 0; k < FDIM; ++k) alpha = fmaf(hiv[k], fc_w[k], alpha);

  float s[FDIM];
#pragma unroll
  for (int f = 0; f < FDIM; ++f) s[f] = 0.f;
#pragma unroll
  for (int k = 0; k < FDIM; ++k) {
#pragma unroll
    for (int f = 0; f < FDIM; ++f) s[f] = fmaf(hiv[k], weight[k * FDIM + f], s[f]);
  }
#pragma unroll
  for (int k = 0; k < FDIM; ++k) {
#pragma unroll
    for (int f = 0; f < FDIM; ++f) s[f] = fmaf(h0v[k], weight[(FDIM + k) * FDIM + f], s[f]);
  }

  float omt = 1.f - theta;
  float oma = 1.f - alpha;
  float ov[FDIM];
#pragma unroll
  for (int f = 0; f < FDIM; ++f) {
    float r = oma * hiv[f] + alpha * h0v[f];
    ov[f] = fmaf(theta, s[f], omt * r) + xv[f];
  }

  float4* o = reinterpret_cast<float4*>(hio + (size_t)i * FDIM);
#pragma unroll
  for (int j = 0; j < 4; ++j) {
    float4 c;
    c.x = ov[4 * j + 0]; c.y = ov[4 * j + 1]; c.z = ov[4 * j + 2]; c.w = ov[4 * j + 3];
    o[j] = c;
  }
}

extern "C" void kernel_launch(void* const* d_in, const int* in_sizes, int n_in,
                              void* d_out, int out_size, void* d_ws, size_t ws_size,
                              hipStream_t stream) {
  const float* x        = (const float*)d_in[0];
  const float* h0       = (const float*)d_in[1];
  const int* adj_row    = (const int*)d_in[2];   // int32 (JAX x64 disabled)
  const int* adj_col    = (const int*)d_in[3];   // int32
  const float* adj_val  = (const float*)d_in[4];
  const float* weight   = (const float*)d_in[5];
  const float* fc_w     = (const float*)d_in[6];
  const float* fc_b     = (const float*)d_in[7];
  const float* lamda    = (const float*)d_in[8];
  const int* lpar       = (const int*)d_in[9];

  int n = in_sizes[0] / FDIM;
  long long nedge = in_sizes[2];
  float* out = (float*)d_out;

  // Zero hi accumulator (d_out) every call — harness poisons once, never
  // re-poisons between timed replays.
  long long n4 = (long long)out_size / 4;
  int zb = (int)((n4 + 255) / 256);
  zero_kernel<<<zb, 256, 0, stream>>>((float4*)out, n4);

  long long ngroups = (nedge + SEG - 1) / SEG;
  long long nblocks = (ngroups + 15) / 16;   // 16 groups (256 threads) / block
  spmm_kernel<<<(int)nblocks, 256, 0, stream>>>(adj_row, adj_col, adj_val, x,
                                                out, nedge);

  int fb = (n + 255) / 256;
  fuse_kernel<<<fb, 256, 0, stream>>>(out, h0, x, weight, fc_w, fc_b,
                                      lamda, lpar, n);
}

// Round 6
// 187.048 us; speedup vs baseline: 1.1518x; 1.1518x over previous
//
#include <hip/hip_runtime.h>

#define FDIM 16

// ---------------------------------------------------------------------------
// Kernel A: build CSR row_ptr from the SORTED COO row array.
// row_ptr[r] = first edge index e with rows[e] >= r;  row_ptr[n] = nedge.
// Each element has exactly one writer (ranges (rows[e-1], rows[e]] disjoint).
// ---------------------------------------------------------------------------
__global__ __launch_bounds__(256) void rowptr_kernel(const int* __restrict__ rows,
                                                     int* __restrict__ row_ptr,
                                                     long long nedge, int n) {
  long long e = (long long)blockIdx.x * blockDim.x + threadIdx.x;
  if (e >= nedge) return;
  int b = rows[e];
  if (e == 0) {
    for (int r = 0; r <= b; ++r) row_ptr[r] = 0;
  } else {
    int a = rows[e - 1];
    for (int r = a + 1; r <= b; ++r) row_ptr[r] = (int)e;
  }
  if (e == nedge - 1) {
    for (int r = b + 1; r <= n; ++r) row_ptr[r] = (int)nedge;
  }
}

// ---------------------------------------------------------------------------
// Kernel B: fused CSR SpMM + GCNII epilogue. One 16-lane group per row
// (lane = feature). 500k independent short chains instead of 62.5k long ones;
// no atomics, no zero-fill, no hi round-trip.
//   hi[f]  = sum_e val[e] * x[col[e], f]          (register accumulate)
//   alpha  = hi . fc_w + fc_b                     (shfl_xor reduce, 16 lanes)
//   s[f]   = sum_k hi[k] W[k,f] + h0[k] W[16+k,f] (shfl broadcast + LDS weight)
//   out    = theta*s + (1-theta)*((1-alpha)hi + alpha h0) + x
// ---------------------------------------------------------------------------
__global__ __launch_bounds__(256) void spmm_fuse_kernel(
    const int* __restrict__ row_ptr,
    const int* __restrict__ cols,
    const float* __restrict__ vals,
    const float* __restrict__ x,
    const float* __restrict__ h0,
    const float* __restrict__ weight,
    const float* __restrict__ fc_w,
    const float* __restrict__ fc_b,
    const float* __restrict__ lamda,
    const int* __restrict__ lpar,
    float* __restrict__ out,
    int n) {
  __shared__ float wsh[2 * FDIM * FDIM];  // 2 KB: the 32x16 weight matrix
  for (int i = threadIdx.x; i < 2 * FDIM * FDIM; i += blockDim.x)
    wsh[i] = weight[i];
  __syncthreads();

  int r = blockIdx.x * (blockDim.x >> 4) + (threadIdx.x >> 4);
  int f = threadIdx.x & 15;
  if (r >= n) return;

  int s = row_ptr[r];
  int t = row_ptr[r + 1];

  float acc = 0.f;
  int e = s;
  for (; e + 8 <= t; e += 8) {
    int c0 = cols[e + 0], c1 = cols[e + 1], c2 = cols[e + 2], c3 = cols[e + 3];
    int c4 = cols[e + 4], c5 = cols[e + 5], c6 = cols[e + 6], c7 = cols[e + 7];
    float v0 = vals[e + 0], v1 = vals[e + 1], v2 = vals[e + 2], v3 = vals[e + 3];
    float v4 = vals[e + 4], v5 = vals[e + 5], v6 = vals[e + 6], v7 = vals[e + 7];
    float g0 = x[c0 * FDIM + f], g1 = x[c1 * FDIM + f];
    float g2 = x[c2 * FDIM + f], g3 = x[c3 * FDIM + f];
    float g4 = x[c4 * FDIM + f], g5 = x[c5 * FDIM + f];
    float g6 = x[c6 * FDIM + f], g7 = x[c7 * FDIM + f];
    acc = fmaf(v0, g0, acc); acc = fmaf(v1, g1, acc);
    acc = fmaf(v2, g2, acc); acc = fmaf(v3, g3, acc);
    acc = fmaf(v4, g4, acc); acc = fmaf(v5, g5, acc);
    acc = fmaf(v6, g6, acc); acc = fmaf(v7, g7, acc);
  }
  if (e + 4 <= t) {
    int c0 = cols[e + 0], c1 = cols[e + 1], c2 = cols[e + 2], c3 = cols[e + 3];
    float v0 = vals[e + 0], v1 = vals[e + 1], v2 = vals[e + 2], v3 = vals[e + 3];
    float g0 = x[c0 * FDIM + f], g1 = x[c1 * FDIM + f];
    float g2 = x[c2 * FDIM + f], g3 = x[c3 * FDIM + f];
    acc = fmaf(v0, g0, acc); acc = fmaf(v1, g1, acc);
    acc = fmaf(v2, g2, acc); acc = fmaf(v3, g3, acc);
    e += 4;
  }
  for (; e < t; ++e)
    acc = fmaf(vals[e], x[cols[e] * FDIM + f], acc);

  // acc == hi[r][f]
  float h0f = h0[(size_t)r * FDIM + f];
  float xf  = x[(size_t)r * FDIM + f];
  float theta = logf(lamda[0] / (float)lpar[0] + 1.0f);

  // alpha = hi . fc_w + fc_b  (reduce across the 16-lane group)
  float av = acc * fc_w[f];
  av += __shfl_xor(av, 1, 16);
  av += __shfl_xor(av, 2, 16);
  av += __shfl_xor(av, 4, 16);
  av += __shfl_xor(av, 8, 16);
  float alpha = av + fc_b[0];

  // s[f] = sum_k hi[k]*W[k,f] + h0[k]*W[16+k,f]
  float sf = 0.f;
#pragma unroll
  for (int k = 0; k < FDIM; ++k) {
    float hk  = __shfl(acc, k, 16);
    float h0k = __shfl(h0f, k, 16);
    sf = fmaf(hk,  wsh[k * FDIM + f], sf);
    sf = fmaf(h0k, wsh[(FDIM + k) * FDIM + f], sf);
  }

  float rr = (1.f - alpha) * acc + alpha * h0f;
  out[(size_t)r * FDIM + f] = fmaf(theta, sf, (1.f - theta) * rr) + xf;
}

extern "C" void kernel_launch(void* const* d_in, const int* in_sizes, int n_in,
                              void* d_out, int out_size, void* d_ws, size_t ws_size,
                              hipStream_t stream) {
  const float* x        = (const float*)d_in[0];
  const float* h0       = (const float*)d_in[1];
  const int* adj_row    = (const int*)d_in[2];   // int32 (JAX x64 disabled)
  const int* adj_col    = (const int*)d_in[3];   // int32
  const float* adj_val  = (const float*)d_in[4];
  const float* weight   = (const float*)d_in[5];
  const float* fc_w     = (const float*)d_in[6];
  const float* fc_b     = (const float*)d_in[7];
  const float* lamda    = (const float*)d_in[8];
  const int* lpar       = (const int*)d_in[9];

  int n = in_sizes[0] / FDIM;
  long long nedge = in_sizes[2];
  float* out = (float*)d_out;
  int* row_ptr = (int*)d_ws;   // (n+1) ints = 2 MB, rebuilt every call

  long long rb = (nedge + 255) / 256;
  rowptr_kernel<<<(int)rb, 256, 0, stream>>>(adj_row, row_ptr, nedge, n);

  int rows_per_block = 256 / FDIM;                 // 16
  int sb = (n + rows_per_block - 1) / rows_per_block;
  spmm_fuse_kernel<<<sb, 256, 0, stream>>>(row_ptr, adj_col, adj_val, x, h0,
                                           weight, fc_w, fc_b, lamda, lpar,
                                           out, n);
}

// Round 7
// 171.839 us; speedup vs baseline: 1.2538x; 1.0885x over previous
//
#include <hip/hip_runtime.h>

#define FDIM 16
#define RPB  16     // rows per block (one 16-lane group per row)
#define CAP  1024   // LDS edge-tile capacity (block span ~256, huge margin)

// ---------------------------------------------------------------------------
// Kernel A: build CSR row_ptr from the SORTED COO row array.
// row_ptr[r] = first edge index e with rows[e] >= r;  row_ptr[n] = nedge.
// ---------------------------------------------------------------------------
__global__ __launch_bounds__(256) void rowptr_kernel(const int* __restrict__ rows,
                                                     int* __restrict__ row_ptr,
                                                     long long nedge, int n) {
  long long e = (long long)blockIdx.x * blockDim.x + threadIdx.x;
  if (e >= nedge) return;
  int b = rows[e];
  if (e == 0) {
    for (int r = 0; r <= b; ++r) row_ptr[r] = 0;
  } else {
    int a = rows[e - 1];
    for (int r = a + 1; r <= b; ++r) row_ptr[r] = (int)e;
  }
  if (e == nedge - 1) {
    for (int r = b + 1; r <= n; ++r) row_ptr[r] = (int)nedge;
  }
}

// ---------------------------------------------------------------------------
// Kernel B: fused CSR SpMM + GCNII epilogue.
// Block = 256 threads = 16 groups, one group per row (lane = feature).
// Phase 1: cooperatively stage the block's contiguous edge span (cols+vals)
//          into LDS with coalesced loads (64 lanes x 4B each).
// Phase 2: each group reads its row's edges from LDS (16-lane broadcast,
//          conflict-free) and issues 8-deep x-gathers (one 64B line/group).
// Epilogue in-register: shfl_xor alpha-reduce, shfl-broadcast 32x16 matmul
// with LDS-staged weight.
// ---------------------------------------------------------------------------
__global__ __launch_bounds__(256) void spmm_fuse_kernel(
    const int* __restrict__ row_ptr,
    const int* __restrict__ cols,
    const float* __restrict__ vals,
    const float* __restrict__ x,
    const float* __restrict__ h0,
    const float* __restrict__ weight,
    const float* __restrict__ fc_w,
    const float* __restrict__ fc_b,
    const float* __restrict__ lamda,
    const int* __restrict__ lpar,
    float* __restrict__ out,
    int n) {
  __shared__ float wsh[2 * FDIM * FDIM];  // 2 KB weight
  __shared__ int   lc[CAP];               // 4 KB cols tile
  __shared__ float lv[CAP];               // 4 KB vals tile
  for (int i = threadIdx.x; i < 2 * FDIM * FDIM; i += blockDim.x)
    wsh[i] = weight[i];

  int g = threadIdx.x >> 4;
  int f = threadIdx.x & 15;
  int R0 = blockIdx.x * RPB;
  int r = R0 + g;
  int Rend = min(R0 + RPB, n);

  int s_blk = row_ptr[R0];
  int t_blk = row_ptr[Rend];
  int s_g = 0, t_g = 0;
  if (r < n) { s_g = row_ptr[r]; t_g = row_ptr[r + 1]; }

  float acc = 0.f;
  for (int t0 = s_blk; t0 < t_blk; t0 += CAP) {
    int t1 = min(t0 + CAP, t_blk);
    __syncthreads();  // previous tile fully consumed before overwrite
    for (int i = t0 + (int)threadIdx.x; i < t1; i += 256) {
      lc[i - t0] = cols[i];   // coalesced: 64 consecutive lanes -> 256B
      lv[i - t0] = vals[i];
    }
    __syncthreads();

    int a = max(s_g, t0), b = min(t_g, t1);
    int e = a;
    for (; e + 8 <= b; e += 8) {
      int j = e - t0;
      int   c0 = lc[j + 0], c1 = lc[j + 1], c2 = lc[j + 2], c3 = lc[j + 3];
      int   c4 = lc[j + 4], c5 = lc[j + 5], c6 = lc[j + 6], c7 = lc[j + 7];
      float v0 = lv[j + 0], v1 = lv[j + 1], v2 = lv[j + 2], v3 = lv[j + 3];
      float v4 = lv[j + 4], v5 = lv[j + 5], v6 = lv[j + 6], v7 = lv[j + 7];
      float g0 = x[c0 * FDIM + f], g1 = x[c1 * FDIM + f];
      float g2 = x[c2 * FDIM + f], g3 = x[c3 * FDIM + f];
      float g4 = x[c4 * FDIM + f], g5 = x[c5 * FDIM + f];
      float g6 = x[c6 * FDIM + f], g7 = x[c7 * FDIM + f];
      acc = fmaf(v0, g0, acc); acc = fmaf(v1, g1, acc);
      acc = fmaf(v2, g2, acc); acc = fmaf(v3, g3, acc);
      acc = fmaf(v4, g4, acc); acc = fmaf(v5, g5, acc);
      acc = fmaf(v6, g6, acc); acc = fmaf(v7, g7, acc);
    }
    if (e + 4 <= b) {
      int j = e - t0;
      int   c0 = lc[j + 0], c1 = lc[j + 1], c2 = lc[j + 2], c3 = lc[j + 3];
      float v0 = lv[j + 0], v1 = lv[j + 1], v2 = lv[j + 2], v3 = lv[j + 3];
      float g0 = x[c0 * FDIM + f], g1 = x[c1 * FDIM + f];
      float g2 = x[c2 * FDIM + f], g3 = x[c3 * FDIM + f];
      acc = fmaf(v0, g0, acc); acc = fmaf(v1, g1, acc);
      acc = fmaf(v2, g2, acc); acc = fmaf(v3, g3, acc);
      e += 4;
    }
    for (; e < b; ++e)
      acc = fmaf(lv[e - t0], x[lc[e - t0] * FDIM + f], acc);
  }
  __syncthreads();  // wsh visibility even if edge span was empty

  if (r >= n) return;

  // acc == hi[r][f]
  float h0f = h0[(size_t)r * FDIM + f];
  float xf  = x[(size_t)r * FDIM + f];
  float theta = logf(lamda[0] / (float)lpar[0] + 1.0f);

  // alpha = hi . fc_w + fc_b  (16-lane reduce)
  float av = acc * fc_w[f];
  av += __shfl_xor(av, 1, 16);
  av += __shfl_xor(av, 2, 16);
  av += __shfl_xor(av, 4, 16);
  av += __shfl_xor(av, 8, 16);
  float alpha = av + fc_b[0];

  // s[f] = sum_k hi[k]*W[k,f] + h0[k]*W[16+k,f]
  float sf = 0.f;
#pragma unroll
  for (int k = 0; k < FDIM; ++k) {
    float hk  = __shfl(acc, k, 16);
    float h0k = __shfl(h0f, k, 16);
    sf = fmaf(hk,  wsh[k * FDIM + f], sf);
    sf = fmaf(h0k, wsh[(FDIM + k) * FDIM + f], sf);
  }

  float rr = (1.f - alpha) * acc + alpha * h0f;
  out[(size_t)r * FDIM + f] = fmaf(theta, sf, (1.f - theta) * rr) + xf;
}

extern "C" void kernel_launch(void* const* d_in, const int* in_sizes, int n_in,
                              void* d_out, int out_size, void* d_ws, size_t ws_size,
                              hipStream_t stream) {
  const float* x        = (const float*)d_in[0];
  const float* h0       = (const float*)d_in[1];
  const int* adj_row    = (const int*)d_in[2];   // int32 (JAX x64 disabled)
  const int* adj_col    = (const int*)d_in[3];   // int32
  const float* adj_val  = (const float*)d_in[4];
  const float* weight   = (const float*)d_in[5];
  const float* fc_w     = (const float*)d_in[6];
  const float* fc_b     = (const float*)d_in[7];
  const float* lamda    = (const float*)d_in[8];
  const int* lpar       = (const int*)d_in[9];

  int n = in_sizes[0] / FDIM;
  long long nedge = in_sizes[2];
  float* out = (float*)d_out;
  int* row_ptr = (int*)d_ws;   // (n+1) ints = 2 MB, rebuilt every call

  long long rb = (nedge + 255) / 256;
  rowptr_kernel<<<(int)rb, 256, 0, stream>>>(adj_row, row_ptr, nedge, n);

  int sb = (n + RPB - 1) / RPB;
  spmm_fuse_kernel<<<sb, 256, 0, stream>>>(row_ptr, adj_col, adj_val, x, h0,
                                           weight, fc_w, fc_b, lamda, lpar,
                                           out, n);
}